// Round 20
// baseline (85.522 us; speedup 1.0000x reference)
//
#include <hip/hip_runtime.h>

// Dims: b=16, n=1024, EMB=1024, INNER=128, HEADS=8, HD=16
#define LOG2E 1.44269504088896340736f
#define QSCALE (0.08838834764831845f * LOG2E)   // INNER^-0.5 * log2(e)

using short8 = __attribute__((ext_vector_type(8))) short;
using f32x4  = __attribute__((ext_vector_type(4))) float;
using f32x16 = __attribute__((ext_vector_type(16))) float;

union U16B { uint4 u; short8 s; };

typedef __attribute__((address_space(3))) unsigned char lds_byte;
typedef const __attribute__((address_space(1))) unsigned char glb_byte;
#define GLOAD16(gp, lp) __builtin_amdgcn_global_load_lds((glb_byte*)(gp), (lds_byte*)(lp), 16, 0, 0)

static __device__ __forceinline__ unsigned short f2bf(float f){
  union { float f; unsigned int i; } c; c.f = f;
  unsigned int i = c.i;
  i += 0x7fffu + ((i >> 16) & 1u);   // RNE
  return (unsigned short)(i >> 16);
}

// ---------------- K1: LayerNorm (blocks 0..4095) + weight cvt (blocks 4096..4351) ----------------
__global__ __launch_bounds__(256) void k_ln(const float* __restrict__ x,
                                            const float* __restrict__ gamma,
                                            const float* __restrict__ beta,
                                            unsigned short* __restrict__ xn,
                                            const float* __restrict__ wqkv,
                                            const float* __restrict__ wproj,
                                            unsigned short* __restrict__ wqkvT,
                                            unsigned short* __restrict__ wprojT){
  if (blockIdx.x < 4096){
    const int tok = (blockIdx.x*256 + threadIdx.x) >> 6;
    const int l = threadIdx.x & 63;
    const float4* xr = (const float4*)(x + (size_t)tok*1024);
    float4 v[4];
    #pragma unroll
    for (int i=0;i<4;i++) v[i] = xr[l + i*64];
    float s = 0.f, s2 = 0.f;
    #pragma unroll
    for (int i=0;i<4;i++){
      s  += v[i].x+v[i].y+v[i].z+v[i].w;
      s2 += v[i].x*v[i].x+v[i].y*v[i].y+v[i].z*v[i].z+v[i].w*v[i].w;
    }
    #pragma unroll
    for (int o=32;o;o>>=1){ s += __shfl_xor(s,o); s2 += __shfl_xor(s2,o); }
    float mu   = s*(1.0f/1024.0f);
    float rstd = rsqrtf(s2*(1.0f/1024.0f) - mu*mu + 1e-5f);
    ushort4* xo = (ushort4*)(xn + (size_t)tok*1024);
    #pragma unroll
    for (int i=0;i<4;i++){
      float4 g = ((const float4*)gamma)[l + i*64];
      float4 b = ((const float4*)beta)[l + i*64];
      ushort4 o;
      o.x = f2bf((v[i].x-mu)*rstd*g.x + b.x);
      o.y = f2bf((v[i].y-mu)*rstd*g.y + b.y);
      o.z = f2bf((v[i].z-mu)*rstd*g.z + b.z);
      o.w = f2bf((v[i].w-mu)*rstd*g.w + b.w);
      xo[l + i*64] = o;
    }
  } else {
    int t = (blockIdx.x - 4096)*256 + threadIdx.x;
    if (t < 49152){
      int n = t>>7, k0 = (t&127)*8;
      float sc = (n < 128) ? QSCALE : 1.0f;
      const float* src = wqkv + (size_t)k0*384 + n;
      ushort4 lo, hi;
      lo.x = f2bf(src[0]*sc);    lo.y = f2bf(src[384]*sc);
      lo.z = f2bf(src[768]*sc);  lo.w = f2bf(src[1152]*sc);
      hi.x = f2bf(src[1536]*sc); hi.y = f2bf(src[1920]*sc);
      hi.z = f2bf(src[2304]*sc); hi.w = f2bf(src[2688]*sc);
      *(ushort4*)(wqkvT + (size_t)n*1024 + k0)     = lo;
      *(ushort4*)(wqkvT + (size_t)n*1024 + k0 + 4) = hi;
    } else {
      int t2 = t - 49152;
      int n = t2>>4, k0 = (t2&15)*8;
      const float* src = wproj + (size_t)k0*1024 + n;
      ushort4 lo, hi;
      lo.x = f2bf(src[0]);    lo.y = f2bf(src[1024]);
      lo.z = f2bf(src[2048]); lo.w = f2bf(src[3072]);
      hi.x = f2bf(src[4096]); hi.y = f2bf(src[5120]);
      hi.z = f2bf(src[6144]); hi.w = f2bf(src[7168]);
      *(ushort4*)(wprojT + (size_t)n*128 + k0)     = lo;
      *(ushort4*)(wprojT + (size_t)n*128 + k0 + 4) = hi;
    }
  }
}

// ---------------- K2: QKV GEMM (M=16384,K=1024,N=384), BM=64 BN=128 BK=64 ----------------
// grid 768 (1-D, XCD-affinity swizzled), 4 waves; double-buffered, counted vmcnt
__global__ __launch_bounds__(256) void k_qkv(const unsigned short* __restrict__ xn,
                                             const unsigned short* __restrict__ wT,
                                             unsigned short* __restrict__ q,
                                             unsigned short* __restrict__ kbuf,
                                             unsigned short* __restrict__ vT){
  __shared__ __align__(16) unsigned short sm[2][64*64 + 128*64]; // 2 x 24KB
  const int tid = threadIdx.x;
  const int w = tid>>6, l = tid&63;
  const int bid = blockIdx.x;
  const int X = bid & 7, j = bid >> 3;          // j in 0..95
  const int g = X*32 + (j/3);                   // m-group 0..255
  const int sec = j % 3;
  const int m0 = g*64;
  const int nb = sec*128;
  const int wm = (w>>1)*32, wn = (w&1)*64;
  f32x4 acc[2][4] = {};

  auto stage = [&](int buf, int k0){
    unsigned short* sA = &sm[buf][0];
    unsigned short* sB = &sm[buf][4096];
    #pragma unroll
    for (int i=0;i<2;i++){
      int chunk = i*256 + tid;
      int row = chunk>>3;
      int ch = (tid&7) ^ (row&7);
      GLOAD16(xn + (size_t)(m0+row)*1024 + k0 + ch*8,
              (char*)sA + (i*256 + w*64)*16);
    }
    #pragma unroll
    for (int i=0;i<4;i++){
      int chunk = i*256 + tid;
      int row = chunk>>3;
      int ch = (tid&7) ^ (row&7);
      GLOAD16(wT + (size_t)(nb+row)*1024 + k0 + ch*8,
              (char*)sB + (i*256 + w*64)*16);
    }
  };

  stage(0, 0);
  for (int t=0; t<16; ++t){
    const int cur = t & 1;
    if (t < 15){
      stage(cur^1, (t+1)<<6);
      asm volatile("s_waitcnt vmcnt(6)" ::: "memory");
    } else {
      asm volatile("s_waitcnt vmcnt(0)" ::: "memory");
    }
    __builtin_amdgcn_s_barrier();
    const unsigned short* sA = &sm[cur][0];
    const unsigned short* sB = &sm[cur][4096];
    #pragma unroll
    for (int s=0; s<2; ++s){
      short8 af[2], bfr[4];
      #pragma unroll
      for (int i=0;i<2;i++){
        int row = wm + i*16 + (l&15);
        U16B ta; ta.u = *(const uint4*)((const char*)sA + row*128 + ((s*64 + (l>>4)*16) ^ ((row&7)<<4)));
        af[i] = ta.s;
      }
      #pragma unroll
      for (int jj=0;jj<4;jj++){
        int col = wn + jj*16 + (l&15);
        U16B tb; tb.u = *(const uint4*)((const char*)sB + col*128 + ((s*64 + (l>>4)*16) ^ ((col&7)<<4)));
        bfr[jj] = tb.s;
      }
      #pragma unroll
      for (int i=0;i<2;i++)
        #pragma unroll
        for (int jj=0;jj<4;jj++)
          acc[i][jj] = __builtin_amdgcn_mfma_f32_16x16x32_bf16(af[i], bfr[jj], acc[i][jj], 0,0,0);
    }
    __builtin_amdgcn_s_barrier();
  }

  const int b  = m0 >> 10;
  const int n0 = m0 & 1023;
  unsigned short* ep = &sm[0][0];
  if (sec < 2){
    #pragma unroll
    for (int fm=0; fm<2; ++fm)
      #pragma unroll
      for (int fn=0; fn<4; ++fn){
        int colf = wn + fn*16 + (l&15);
        #pragma unroll
        for (int i=0;i<4;i++){
          int row = wm + fm*16 + (l>>4)*4 + i;
          *(unsigned short*)((char*)ep + row*256 + ((2*colf) ^ ((row&15)<<4))) = f2bf(acc[fm][fn][i]);
        }
      }
    __syncthreads();
    unsigned short* dst = (sec==0) ? q : kbuf;
    #pragma unroll
    for (int it=0; it<4; ++it){
      int chunk = it*256 + tid;
      int tokl = chunk>>4, cc = chunk&15;
      uint4 vv = *(const uint4*)((const char*)ep + tokl*256 + ((cc*16) ^ ((tokl&15)<<4)));
      int h = cc>>1, d0 = (cc&1)*8;
      *(uint4*)(dst + ((size_t)(b*8 + h)*1024 + n0 + tokl)*16 + d0) = vv;
    }
  } else {
    // vT tile-contiguous layout: vT[bh][tile32][d16][32 perm tokens] (1KB per tile, coalesced attn reads)
    #pragma unroll
    for (int fm=0; fm<2; ++fm)
      #pragma unroll
      for (int fn=0; fn<4; ++fn){
        int colf = wn + fn*16 + (l&15);
        int r0 = wm + fm*16 + (l>>4)*4;
        ushort4 pk;
        pk.x = f2bf(acc[fm][fn][0]); pk.y = f2bf(acc[fm][fn][1]);
        pk.z = f2bf(acc[fm][fn][2]); pk.w = f2bf(acc[fm][fn][3]);
        *(ushort4*)((char*)ep + colf*128 + ((2*r0) ^ ((colf&7)<<4))) = pk;
      }
    __syncthreads();
    #pragma unroll
    for (int it=0; it<4; ++it){
      int chunk = it*256 + tid;
      int f = chunk>>3, cc = chunk&7;
      uint4 vv = *(const uint4*)((const char*)ep + f*128 + ((cc*16) ^ ((f&7)<<4)));
      int h = f>>4, d = f&15;
      int tile = (n0>>5) + (cc>>2);              // global 32-token tile
      int pos1 = (cc&1)*4 + (cc&2)*8;            // perm position of first 4 tokens
      unsigned short* dp = vT + ((size_t)(b*8 + h)*32 + tile)*512 + d*32 + pos1;
      *(uint2*)dp       = make_uint2(vv.x, vv.y);
      *(uint2*)(dp + 8) = make_uint2(vv.z, vv.w);  // next 4 tokens at pos1+8
    }
  }
}

// ---------------- K3: flash attention, delayed-PV pipeline + tile-contiguous V ----------------
// grid (128 bh, 8 qc), 4 waves x 32 q-rows
__global__ __launch_bounds__(256) void k_attn(const unsigned short* __restrict__ q,
                                              const unsigned short* __restrict__ kbuf,
                                              const unsigned short* __restrict__ vT,
                                              unsigned short* __restrict__ aout){
  const int bh = blockIdx.x;
  const int qc = blockIdx.y;
  const int w = threadIdx.x>>6, l = threadIdx.x&63;
  const int l31 = l&31, hi = l>>5;
  const int h = bh & 7;
  const int qrow = qc*128 + w*32 + l31;
  U16B qf_u; qf_u.u = *(const uint4*)(q + ((size_t)bh*1024 + qrow)*16 + hi*8);
  const short8 qf = qf_u.s;
  const unsigned short* kptr = kbuf + (size_t)bh*16384 + (size_t)l31*16 + hi*8;
  const unsigned short* vptr = vT + (size_t)bh*16384 + (size_t)(l31 & 15)*32 + hi*8;
  const bool vok = (l31 < 16);
  const unsigned int ob = ((l31==16)||(l31==20)) ? 0x3F803F80u : 0u;
  const uint4 cvu = make_uint4(ob, ob, ob, ob);
  f32x16 acc = {};
  const f32x16 zz = {};

  U16B kf; kf.u = *(const uint4*)kptr; kptr += 512;
  U16B kn; kn.u = *(const uint4*)kptr; kptr += 512;
  f32x16 sv = __builtin_amdgcn_mfma_f32_32x32x16_bf16(kf.s, qf, zz, 0,0,0);
  unsigned int u8_0=0,u8_1=0,u8_2=0,u8_3=0,u8_4=0,u8_5=0,u8_6=0,u8_7=0;
  U16B vp0, vp1; vp0.u = cvu; vp1.u = cvu;

  for (int t=0; t<32; ++t){
    U16B knn; knn.u = *(const uint4*)kptr; kptr += 512;
    U16B vn0, vn1; vn0.u = cvu; vn1.u = cvu;
    if (vok){ vn0.u = *(const uint4*)vptr; vn1.u = *(const uint4*)(vptr + 16); }
    vptr += 512;
    f32x16 svn = __builtin_amdgcn_mfma_f32_32x32x16_bf16(kn.s, qf, zz, 0,0,0);
    unsigned int un0,un1,un2,un3,un4,un5,un6,un7;
    {
      float a,b;
      a=__builtin_amdgcn_exp2f(sv[0]);  b=__builtin_amdgcn_exp2f(sv[1]);
      asm("v_cvt_pk_bf16_f32 %0, %1, %2" : "=v"(un0) : "v"(a), "v"(b));
      a=__builtin_amdgcn_exp2f(sv[2]);  b=__builtin_amdgcn_exp2f(sv[3]);
      asm("v_cvt_pk_bf16_f32 %0, %1, %2" : "=v"(un1) : "v"(a), "v"(b));
      a=__builtin_amdgcn_exp2f(sv[4]);  b=__builtin_amdgcn_exp2f(sv[5]);
      asm("v_cvt_pk_bf16_f32 %0, %1, %2" : "=v"(un2) : "v"(a), "v"(b));
      a=__builtin_amdgcn_exp2f(sv[6]);  b=__builtin_amdgcn_exp2f(sv[7]);
      asm("v_cvt_pk_bf16_f32 %0, %1, %2" : "=v"(un3) : "v"(a), "v"(b));
      a=__builtin_amdgcn_exp2f(sv[8]);  b=__builtin_amdgcn_exp2f(sv[9]);
      asm("v_cvt_pk_bf16_f32 %0, %1, %2" : "=v"(un4) : "v"(a), "v"(b));
      a=__builtin_amdgcn_exp2f(sv[10]); b=__builtin_amdgcn_exp2f(sv[11]);
      asm("v_cvt_pk_bf16_f32 %0, %1, %2" : "=v"(un5) : "v"(a), "v"(b));
      a=__builtin_amdgcn_exp2f(sv[12]); b=__builtin_amdgcn_exp2f(sv[13]);
      asm("v_cvt_pk_bf16_f32 %0, %1, %2" : "=v"(un6) : "v"(a), "v"(b));
      a=__builtin_amdgcn_exp2f(sv[14]); b=__builtin_amdgcn_exp2f(sv[15]);
      asm("v_cvt_pk_bf16_f32 %0, %1, %2" : "=v"(un7) : "v"(a), "v"(b));
    }
    U16B p0, p1;
    p0.u.x = u8_0; p0.u.y = u8_1; p0.u.z = u8_2; p0.u.w = u8_3;
    p1.u.x = u8_4; p1.u.y = u8_5; p1.u.z = u8_6; p1.u.w = u8_7;
    __builtin_amdgcn_s_setprio(1);
    acc = __builtin_amdgcn_mfma_f32_32x32x16_bf16(vp0.s, p0.s, acc, 0,0,0);
    acc = __builtin_amdgcn_mfma_f32_32x32x16_bf16(vp1.s, p1.s, acc, 0,0,0);
    __builtin_amdgcn_s_setprio(0);
    sv = svn; kn = knn;
    u8_0=un0; u8_1=un1; u8_2=un2; u8_3=un3; u8_4=un4; u8_5=un5; u8_6=un6; u8_7=un7;
    vp0 = vn0; vp1 = vn1;
  }
  {
    U16B p0, p1;
    p0.u.x = u8_0; p0.u.y = u8_1; p0.u.z = u8_2; p0.u.w = u8_3;
    p1.u.x = u8_4; p1.u.y = u8_5; p1.u.z = u8_6; p1.u.w = u8_7;
    acc = __builtin_amdgcn_mfma_f32_32x32x16_bf16(vp0.s, p0.s, acc, 0,0,0);
    acc = __builtin_amdgcn_mfma_f32_32x32x16_bf16(vp1.s, p1.s, acc, 0,0,0);
  }
  float inv = 1.0f/acc[8];
  const size_t tok = (size_t)(bh>>3)*1024 + qrow;
  ushort4 o;
  o.x = f2bf(acc[0]*inv); o.y = f2bf(acc[1]*inv); o.z = f2bf(acc[2]*inv); o.w = f2bf(acc[3]*inv);
  *(ushort4*)(aout + tok*128 + h*16 + hi*4) = o;
  o.x = f2bf(acc[4]*inv); o.y = f2bf(acc[5]*inv); o.z = f2bf(acc[6]*inv); o.w = f2bf(acc[7]*inv);
  *(ushort4*)(aout + tok*128 + h*16 + 8 + hi*4) = o;
}

// ---------------- K4: out-projection (M=16384,K=128,N=1024) + bias ----------------
__global__ __launch_bounds__(256) void k_proj(const unsigned short* __restrict__ aout,
                                              const unsigned short* __restrict__ wT, // [1024 n][128 k]
                                              const float* __restrict__ bias,
                                              float* __restrict__ out){
  __shared__ __align__(16) unsigned short sA[128*128]; // [tok][k], 256B rows, XOR (row&15)<<4
  __shared__ __align__(16) unsigned short sB[128*128]; // [n][k], same
  const int tid = threadIdx.x;
  const int w = tid>>6, l = tid&63;
  const int m0 = blockIdx.x*128, nb = blockIdx.y*128;
  #pragma unroll
  for (int i=0;i<8;i++){
    int chunk = i*256 + tid;
    int row = chunk>>4;
    int ch = (tid&15) ^ (row&15);
    GLOAD16(aout + (size_t)(m0+row)*128 + ch*8, (char*)sA + (i*256 + w*64)*16);
  }
  #pragma unroll
  for (int i=0;i<8;i++){
    int chunk = i*256 + tid;
    int row = chunk>>4;
    int ch = (tid&15) ^ (row&15);
    GLOAD16(wT + (size_t)(nb+row)*128 + ch*8, (char*)sB + (i*256 + w*64)*16);
  }
  __syncthreads();
  const int wm = (w>>1)*64, wn = (w&1)*64;
  f32x4 acc[4][4] = {};
  #pragma unroll
  for (int s=0; s<4; ++s){
    short8 af[4], bfr[4];
    #pragma unroll
    for (int i=0;i<4;i++){
      int row = wm + i*16 + (l&15);
      U16B ta; ta.u = *(const uint4*)((const char*)sA + row*256 + ((s*64 + (l>>4)*16) ^ ((row&15)<<4)));
      af[i] = ta.s;
      int col = wn + i*16 + (l&15);
      U16B tb; tb.u = *(const uint4*)((const char*)sB + col*256 + ((s*64 + (l>>4)*16) ^ ((col&15)<<4)));
      bfr[i] = tb.s;
    }
    #pragma unroll
    for (int i=0;i<4;i++)
      #pragma unroll
      for (int j=0;j<4;j++)
        acc[i][j] = __builtin_amdgcn_mfma_f32_16x16x32_bf16(af[i], bfr[j], acc[i][j], 0,0,0);
  }
  #pragma unroll
  for (int fn=0; fn<4; ++fn){
    int col = nb + wn + fn*16 + (l&15);
    float bv = bias[col];
    #pragma unroll
    for (int fm=0; fm<4; ++fm)
      #pragma unroll
      for (int i=0;i<4;i++)
        out[(size_t)(m0 + wm + fm*16 + (l>>4)*4 + i)*1024 + col] = acc[fm][fn][i] + bv;
  }
}

extern "C" void kernel_launch(void* const* d_in, const int* in_sizes, int n_in,
                              void* d_out, int out_size, void* d_ws, size_t ws_size,
                              hipStream_t stream){
  (void)in_sizes; (void)n_in; (void)out_size; (void)ws_size;
  const float* x     = (const float*)d_in[0];
  const float* gamma = (const float*)d_in[1];
  const float* beta  = (const float*)d_in[2];
  const float* wqkv  = (const float*)d_in[3];
  const float* wproj = (const float*)d_in[4];
  const float* bias  = (const float*)d_in[5];
  float* out = (float*)d_out;
  char* ws = (char*)d_ws;
  unsigned short* xn = (unsigned short*)ws;                                  // 32 MB
  unsigned short* q  = (unsigned short*)(ws + 33554432);                     // 4 MB
  unsigned short* kb = (unsigned short*)(ws + 33554432 + 4194304);           // 4 MB
  unsigned short* vT = (unsigned short*)(ws + 33554432 + 2*4194304);         // 4 MB
  unsigned short* ao = (unsigned short*)(ws + 33554432 + 3*4194304);         // 4 MB
  unsigned short* wqkvT = (unsigned short*)(ws + 33554432 + 4*4194304);      // 768 KB
  unsigned short* wprojT = (unsigned short*)(ws + 33554432 + 4*4194304 + 786432); // 256 KB
  k_ln  <<<dim3(4352), dim3(256), 0, stream>>>(x, gamma, beta, xn, wqkv, wproj, wqkvT, wprojT);
  k_qkv <<<dim3(768), dim3(256), 0, stream>>>(xn, wqkvT, q, kb, vT);
  k_attn<<<dim3(128,8), dim3(256), 0, stream>>>(q, kb, vT, ao);
  k_proj<<<dim3(128,8), dim3(256), 0, stream>>>(ao, wprojT, bias, out);
}

// Round 21
// 82.997 us; speedup vs baseline: 1.0304x; 1.0304x over previous
//
#include <hip/hip_runtime.h>

// Dims: b=16, n=1024, EMB=1024, INNER=128, HEADS=8, HD=16
#define LOG2E 1.44269504088896340736f
#define QSCALE (0.08838834764831845f * LOG2E)   // INNER^-0.5 * log2(e)

using short8 = __attribute__((ext_vector_type(8))) short;
using f32x4  = __attribute__((ext_vector_type(4))) float;
using f32x16 = __attribute__((ext_vector_type(16))) float;

union U16B { uint4 u; short8 s; };

typedef __attribute__((address_space(3))) unsigned char lds_byte;
typedef const __attribute__((address_space(1))) unsigned char glb_byte;
#define GLOAD16(gp, lp) __builtin_amdgcn_global_load_lds((glb_byte*)(gp), (lds_byte*)(lp), 16, 0, 0)

static __device__ __forceinline__ unsigned short f2bf(float f){
  union { float f; unsigned int i; } c; c.f = f;
  unsigned int i = c.i;
  i += 0x7fffu + ((i >> 16) & 1u);   // RNE
  return (unsigned short)(i >> 16);
}

// ---------------- K1: LayerNorm (0..4095) + weight cvt (4096..4351) + vT2 constant fill (4352..4607) ----------------
__global__ __launch_bounds__(256) void k_ln(const float* __restrict__ x,
                                            const float* __restrict__ gamma,
                                            const float* __restrict__ beta,
                                            unsigned short* __restrict__ xn,
                                            const float* __restrict__ wqkv,
                                            const float* __restrict__ wproj,
                                            unsigned short* __restrict__ wqkvT,
                                            unsigned short* __restrict__ wprojT,
                                            unsigned short* __restrict__ vT2){
  if (blockIdx.x < 4096){
    const int tok = (blockIdx.x*256 + threadIdx.x) >> 6;
    const int l = threadIdx.x & 63;
    const float4* xr = (const float4*)(x + (size_t)tok*1024);
    float4 v[4];
    #pragma unroll
    for (int i=0;i<4;i++) v[i] = xr[l + i*64];
    float s = 0.f, s2 = 0.f;
    #pragma unroll
    for (int i=0;i<4;i++){
      s  += v[i].x+v[i].y+v[i].z+v[i].w;
      s2 += v[i].x*v[i].x+v[i].y*v[i].y+v[i].z*v[i].z+v[i].w*v[i].w;
    }
    #pragma unroll
    for (int o=32;o;o>>=1){ s += __shfl_xor(s,o); s2 += __shfl_xor(s2,o); }
    float mu   = s*(1.0f/1024.0f);
    float rstd = rsqrtf(s2*(1.0f/1024.0f) - mu*mu + 1e-5f);
    ushort4* xo = (ushort4*)(xn + (size_t)tok*1024);
    #pragma unroll
    for (int i=0;i<4;i++){
      float4 g = ((const float4*)gamma)[l + i*64];
      float4 b = ((const float4*)beta)[l + i*64];
      ushort4 o;
      o.x = f2bf((v[i].x-mu)*rstd*g.x + b.x);
      o.y = f2bf((v[i].y-mu)*rstd*g.y + b.y);
      o.z = f2bf((v[i].z-mu)*rstd*g.z + b.z);
      o.w = f2bf((v[i].w-mu)*rstd*g.w + b.w);
      xo[l + i*64] = o;
    }
  } else if (blockIdx.x < 4352){
    int t = (blockIdx.x - 4096)*256 + threadIdx.x;
    if (t < 49152){
      int n = t>>7, k0 = (t&127)*8;
      float sc = (n < 128) ? QSCALE : 1.0f;
      const float* src = wqkv + (size_t)k0*384 + n;
      ushort4 lo, hi;
      lo.x = f2bf(src[0]*sc);    lo.y = f2bf(src[384]*sc);
      lo.z = f2bf(src[768]*sc);  lo.w = f2bf(src[1152]*sc);
      hi.x = f2bf(src[1536]*sc); hi.y = f2bf(src[1920]*sc);
      hi.z = f2bf(src[2304]*sc); hi.w = f2bf(src[2688]*sc);
      *(ushort4*)(wqkvT + (size_t)n*1024 + k0)     = lo;
      *(ushort4*)(wqkvT + (size_t)n*1024 + k0 + 4) = hi;
    } else {
      int t2 = t - 49152;
      int n = t2>>4, k0 = (t2&15)*8;
      const float* src = wproj + (size_t)k0*1024 + n;
      ushort4 lo, hi;
      lo.x = f2bf(src[0]);    lo.y = f2bf(src[1024]);
      lo.z = f2bf(src[2048]); lo.w = f2bf(src[3072]);
      hi.x = f2bf(src[4096]); hi.y = f2bf(src[5120]);
      hi.z = f2bf(src[6144]); hi.w = f2bf(src[7168]);
      *(ushort4*)(wprojT + (size_t)n*128 + k0)     = lo;
      *(ushort4*)(wprojT + (size_t)n*128 + k0 + 4) = hi;
    }
  } else {
    // vT2 constant rows (A-operand rows 16..31 of every 2KB tile):
    // per tile: 4 blocks of 128 ushorts at bases {128,384,640,896}; within a block,
    // row l31=16+w occupies ushorts w*8..w*8+7; ones (bf16 1.0) iff w==0 (l31=16) or w==4 (l31=20).
    #pragma unroll
    for (int i=0;i<4;i++){
      int c = (blockIdx.x - 4352)*1024 + i*256 + threadIdx.x;  // 262144 uint4 chunks
      int tile = c>>6, k = c&63;
      int sub = k>>4, w = k&15;
      unsigned int val = (w==0 || w==4) ? 0x3F803F80u : 0u;
      unsigned short* dp = vT2 + (size_t)tile*1024 + 128 + sub*256 + w*8;
      *(uint4*)dp = make_uint4(val,val,val,val);
    }
  }
}

// ---------------- K2: QKV GEMM (M=16384,K=1024,N=384), BM=64 BN=128 BK=64 ----------------
// grid 768 (1-D, XCD-affinity swizzled), 4 waves; double-buffered, counted vmcnt
__global__ __launch_bounds__(256) void k_qkv(const unsigned short* __restrict__ xn,
                                             const unsigned short* __restrict__ wT,
                                             unsigned short* __restrict__ q,
                                             unsigned short* __restrict__ kbuf,
                                             unsigned short* __restrict__ vT2){
  __shared__ __align__(16) unsigned short sm[2][64*64 + 128*64]; // 2 x 24KB
  const int tid = threadIdx.x;
  const int w = tid>>6, l = tid&63;
  const int bid = blockIdx.x;
  const int X = bid & 7, j = bid >> 3;          // j in 0..95
  const int g = X*32 + (j/3);                   // m-group 0..255
  const int sec = j % 3;
  const int m0 = g*64;
  const int nb = sec*128;
  const int wm = (w>>1)*32, wn = (w&1)*64;
  f32x4 acc[2][4] = {};

  auto stage = [&](int buf, int k0){
    unsigned short* sA = &sm[buf][0];
    unsigned short* sB = &sm[buf][4096];
    #pragma unroll
    for (int i=0;i<2;i++){
      int chunk = i*256 + tid;
      int row = chunk>>3;
      int ch = (tid&7) ^ (row&7);
      GLOAD16(xn + (size_t)(m0+row)*1024 + k0 + ch*8,
              (char*)sA + (i*256 + w*64)*16);
    }
    #pragma unroll
    for (int i=0;i<4;i++){
      int chunk = i*256 + tid;
      int row = chunk>>3;
      int ch = (tid&7) ^ (row&7);
      GLOAD16(wT + (size_t)(nb+row)*1024 + k0 + ch*8,
              (char*)sB + (i*256 + w*64)*16);
    }
  };

  stage(0, 0);
  for (int t=0; t<16; ++t){
    const int cur = t & 1;
    if (t < 15){
      stage(cur^1, (t+1)<<6);
      asm volatile("s_waitcnt vmcnt(6)" ::: "memory");
    } else {
      asm volatile("s_waitcnt vmcnt(0)" ::: "memory");
    }
    __builtin_amdgcn_s_barrier();
    const unsigned short* sA = &sm[cur][0];
    const unsigned short* sB = &sm[cur][4096];
    #pragma unroll
    for (int s=0; s<2; ++s){
      short8 af[2], bfr[4];
      #pragma unroll
      for (int i=0;i<2;i++){
        int row = wm + i*16 + (l&15);
        U16B ta; ta.u = *(const uint4*)((const char*)sA + row*128 + ((s*64 + (l>>4)*16) ^ ((row&7)<<4)));
        af[i] = ta.s;
      }
      #pragma unroll
      for (int jj=0;jj<4;jj++){
        int col = wn + jj*16 + (l&15);
        U16B tb; tb.u = *(const uint4*)((const char*)sB + col*128 + ((s*64 + (l>>4)*16) ^ ((col&7)<<4)));
        bfr[jj] = tb.s;
      }
      #pragma unroll
      for (int i=0;i<2;i++)
        #pragma unroll
        for (int jj=0;jj<4;jj++)
          acc[i][jj] = __builtin_amdgcn_mfma_f32_16x16x32_bf16(af[i], bfr[jj], acc[i][jj], 0,0,0);
    }
    __builtin_amdgcn_s_barrier();
  }

  const int b  = m0 >> 10;
  const int n0 = m0 & 1023;
  unsigned short* ep = &sm[0][0];
  if (sec < 2){
    #pragma unroll
    for (int fm=0; fm<2; ++fm)
      #pragma unroll
      for (int fn=0; fn<4; ++fn){
        int colf = wn + fn*16 + (l&15);
        #pragma unroll
        for (int i=0;i<4;i++){
          int row = wm + fm*16 + (l>>4)*4 + i;
          *(unsigned short*)((char*)ep + row*256 + ((2*colf) ^ ((row&15)<<4))) = f2bf(acc[fm][fn][i]);
        }
      }
    __syncthreads();
    unsigned short* dst = (sec==0) ? q : kbuf;
    #pragma unroll
    for (int it=0; it<4; ++it){
      int chunk = it*256 + tid;
      int tokl = chunk>>4, cc = chunk&15;
      uint4 vv = *(const uint4*)((const char*)ep + tokl*256 + ((cc*16) ^ ((tokl&15)<<4)));
      int h = cc>>1, d0 = (cc&1)*8;
      *(uint4*)(dst + ((size_t)(b*8 + h)*1024 + n0 + tokl)*16 + d0) = vv;
    }
  } else {
    // vT2 fragment-ordered layout: tile = 2KB = 32 A-rows x 32 token-slots;
    // element (d, pos q..q+3 runs) at ushort off = (q&24)*32 + d*8 + (q&4).
    // Token->position permutation identical to R17 (pos1 = (cc&1)*4 + (cc&2)*8).
    #pragma unroll
    for (int fm=0; fm<2; ++fm)
      #pragma unroll
      for (int fn=0; fn<4; ++fn){
        int colf = wn + fn*16 + (l&15);
        int r0 = wm + fm*16 + (l>>4)*4;
        ushort4 pk;
        pk.x = f2bf(acc[fm][fn][0]); pk.y = f2bf(acc[fm][fn][1]);
        pk.z = f2bf(acc[fm][fn][2]); pk.w = f2bf(acc[fm][fn][3]);
        *(ushort4*)((char*)ep + colf*128 + ((2*r0) ^ ((colf&7)<<4))) = pk;
      }
    __syncthreads();
    #pragma unroll
    for (int it=0; it<4; ++it){
      int chunk = it*256 + tid;
      int f = chunk>>3, cc = chunk&7;
      uint4 vv = *(const uint4*)((const char*)ep + f*128 + ((cc*16) ^ ((f&7)<<4)));
      int h = f>>4, d = f&15;
      int tile = (n0>>5) + (cc>>2);
      int q1 = (cc&1)*4 + (cc&2)*8;
      int q2 = q1 + 8;
      unsigned short* tb = vT2 + ((size_t)(b*8 + h)*32 + tile)*1024 + d*8;
      *(uint2*)(tb + (q1&24)*32 + (q1&4)) = make_uint2(vv.x, vv.y);
      *(uint2*)(tb + (q2&24)*32 + (q2&4)) = make_uint2(vv.z, vv.w);
    }
  }
}

// ---------------- K3: flash attention, delayed-PV + fragment-ordered V (single-segment loads) ----------------
// grid (128 bh, 8 qc), 4 waves x 32 q-rows
__global__ __launch_bounds__(256) void k_attn(const unsigned short* __restrict__ q,
                                              const unsigned short* __restrict__ kbuf,
                                              const unsigned short* __restrict__ vT2,
                                              unsigned short* __restrict__ aout){
  const int bh = blockIdx.x;
  const int qc = blockIdx.y;
  const int w = threadIdx.x>>6, l = threadIdx.x&63;
  const int l31 = l&31, hi = l>>5;
  const int h = bh & 7;
  const int qrow = qc*128 + w*32 + l31;
  U16B qf_u; qf_u.u = *(const uint4*)(q + ((size_t)bh*1024 + qrow)*16 + hi*8);
  const short8 qf = qf_u.s;
  const unsigned short* kptr = kbuf + (size_t)bh*16384 + (size_t)l31*16 + hi*8;
  // fragment-ordered V: lane l's 16B at l*8 ushorts within each 1KB half-tile
  const unsigned short* vptr = vT2 + (size_t)bh*32768 + (size_t)l*8;
  f32x16 acc = {};
  const f32x16 zz = {};

  U16B kf; kf.u = *(const uint4*)kptr; kptr += 512;
  U16B kn; kn.u = *(const uint4*)kptr; kptr += 512;
  f32x16 sv = __builtin_amdgcn_mfma_f32_32x32x16_bf16(kf.s, qf, zz, 0,0,0);
  unsigned int u8_0=0,u8_1=0,u8_2=0,u8_3=0,u8_4=0,u8_5=0,u8_6=0,u8_7=0;
  U16B vp0, vp1;
  vp0.u = make_uint4(0,0,0,0); vp1.u = make_uint4(0,0,0,0);   // P(-1)=0, values unused

  for (int t=0; t<32; ++t){
    U16B knn; knn.u = *(const uint4*)kptr; kptr += 512;
    U16B vn0, vn1;
    vn0.u = *(const uint4*)vptr;
    vn1.u = *(const uint4*)(vptr + 512);
    vptr += 1024;
    f32x16 svn = __builtin_amdgcn_mfma_f32_32x32x16_bf16(kn.s, qf, zz, 0,0,0);
    unsigned int un0,un1,un2,un3,un4,un5,un6,un7;
    {
      float a,b;
      a=__builtin_amdgcn_exp2f(sv[0]);  b=__builtin_amdgcn_exp2f(sv[1]);
      asm("v_cvt_pk_bf16_f32 %0, %1, %2" : "=v"(un0) : "v"(a), "v"(b));
      a=__builtin_amdgcn_exp2f(sv[2]);  b=__builtin_amdgcn_exp2f(sv[3]);
      asm("v_cvt_pk_bf16_f32 %0, %1, %2" : "=v"(un1) : "v"(a), "v"(b));
      a=__builtin_amdgcn_exp2f(sv[4]);  b=__builtin_amdgcn_exp2f(sv[5]);
      asm("v_cvt_pk_bf16_f32 %0, %1, %2" : "=v"(un2) : "v"(a), "v"(b));
      a=__builtin_amdgcn_exp2f(sv[6]);  b=__builtin_amdgcn_exp2f(sv[7]);
      asm("v_cvt_pk_bf16_f32 %0, %1, %2" : "=v"(un3) : "v"(a), "v"(b));
      a=__builtin_amdgcn_exp2f(sv[8]);  b=__builtin_amdgcn_exp2f(sv[9]);
      asm("v_cvt_pk_bf16_f32 %0, %1, %2" : "=v"(un4) : "v"(a), "v"(b));
      a=__builtin_amdgcn_exp2f(sv[10]); b=__builtin_amdgcn_exp2f(sv[11]);
      asm("v_cvt_pk_bf16_f32 %0, %1, %2" : "=v"(un5) : "v"(a), "v"(b));
      a=__builtin_amdgcn_exp2f(sv[12]); b=__builtin_amdgcn_exp2f(sv[13]);
      asm("v_cvt_pk_bf16_f32 %0, %1, %2" : "=v"(un6) : "v"(a), "v"(b));
      a=__builtin_amdgcn_exp2f(sv[14]); b=__builtin_amdgcn_exp2f(sv[15]);
      asm("v_cvt_pk_bf16_f32 %0, %1, %2" : "=v"(un7) : "v"(a), "v"(b));
    }
    U16B p0, p1;
    p0.u.x = u8_0; p0.u.y = u8_1; p0.u.z = u8_2; p0.u.w = u8_3;
    p1.u.x = u8_4; p1.u.y = u8_5; p1.u.z = u8_6; p1.u.w = u8_7;
    __builtin_amdgcn_s_setprio(1);
    acc = __builtin_amdgcn_mfma_f32_32x32x16_bf16(vp0.s, p0.s, acc, 0,0,0);
    acc = __builtin_amdgcn_mfma_f32_32x32x16_bf16(vp1.s, p1.s, acc, 0,0,0);
    __builtin_amdgcn_s_setprio(0);
    sv = svn; kn = knn;
    u8_0=un0; u8_1=un1; u8_2=un2; u8_3=un3; u8_4=un4; u8_5=un5; u8_6=un6; u8_7=un7;
    vp0 = vn0; vp1 = vn1;
  }
  {
    U16B p0, p1;
    p0.u.x = u8_0; p0.u.y = u8_1; p0.u.z = u8_2; p0.u.w = u8_3;
    p1.u.x = u8_4; p1.u.y = u8_5; p1.u.z = u8_6; p1.u.w = u8_7;
    acc = __builtin_amdgcn_mfma_f32_32x32x16_bf16(vp0.s, p0.s, acc, 0,0,0);
    acc = __builtin_amdgcn_mfma_f32_32x32x16_bf16(vp1.s, p1.s, acc, 0,0,0);
  }
  float inv = 1.0f/acc[8];
  const size_t tok = (size_t)(bh>>3)*1024 + qrow;
  ushort4 o;
  o.x = f2bf(acc[0]*inv); o.y = f2bf(acc[1]*inv); o.z = f2bf(acc[2]*inv); o.w = f2bf(acc[3]*inv);
  *(ushort4*)(aout + tok*128 + h*16 + hi*4) = o;
  o.x = f2bf(acc[4]*inv); o.y = f2bf(acc[5]*inv); o.z = f2bf(acc[6]*inv); o.w = f2bf(acc[7]*inv);
  *(ushort4*)(aout + tok*128 + h*16 + 8 + hi*4) = o;
}

// ---------------- K4: out-projection (M=16384,K=128,N=1024) + bias ----------------
__global__ __launch_bounds__(256) void k_proj(const unsigned short* __restrict__ aout,
                                              const unsigned short* __restrict__ wT, // [1024 n][128 k]
                                              const float* __restrict__ bias,
                                              float* __restrict__ out){
  __shared__ __align__(16) unsigned short sA[128*128]; // [tok][k], 256B rows, XOR (row&15)<<4
  __shared__ __align__(16) unsigned short sB[128*128]; // [n][k], same
  const int tid = threadIdx.x;
  const int w = tid>>6, l = tid&63;
  const int m0 = blockIdx.x*128, nb = blockIdx.y*128;
  #pragma unroll
  for (int i=0;i<8;i++){
    int chunk = i*256 + tid;
    int row = chunk>>4;
    int ch = (tid&15) ^ (row&15);
    GLOAD16(aout + (size_t)(m0+row)*128 + ch*8, (char*)sA + (i*256 + w*64)*16);
  }
  #pragma unroll
  for (int i=0;i<8;i++){
    int chunk = i*256 + tid;
    int row = chunk>>4;
    int ch = (tid&15) ^ (row&15);
    GLOAD16(wT + (size_t)(nb+row)*128 + ch*8, (char*)sB + (i*256 + w*64)*16);
  }
  __syncthreads();
  const int wm = (w>>1)*64, wn = (w&1)*64;
  f32x4 acc[4][4] = {};
  #pragma unroll
  for (int s=0; s<4; ++s){
    short8 af[4], bfr[4];
    #pragma unroll
    for (int i=0;i<4;i++){
      int row = wm + i*16 + (l&15);
      U16B ta; ta.u = *(const uint4*)((const char*)sA + row*256 + ((s*64 + (l>>4)*16) ^ ((row&15)<<4)));
      af[i] = ta.s;
      int col = wn + i*16 + (l&15);
      U16B tb; tb.u = *(const uint4*)((const char*)sB + col*256 + ((s*64 + (l>>4)*16) ^ ((col&15)<<4)));
      bfr[i] = tb.s;
    }
    #pragma unroll
    for (int i=0;i<4;i++)
      #pragma unroll
      for (int j=0;j<4;j++)
        acc[i][j] = __builtin_amdgcn_mfma_f32_16x16x32_bf16(af[i], bfr[j], acc[i][j], 0,0,0);
  }
  #pragma unroll
  for (int fn=0; fn<4; ++fn){
    int col = nb + wn + fn*16 + (l&15);
    float bv = bias[col];
    #pragma unroll
    for (int fm=0; fm<4; ++fm)
      #pragma unroll
      for (int i=0;i<4;i++)
        out[(size_t)(m0 + wm + fm*16 + (l>>4)*4 + i)*1024 + col] = acc[fm][fn][i] + bv;
  }
}

extern "C" void kernel_launch(void* const* d_in, const int* in_sizes, int n_in,
                              void* d_out, int out_size, void* d_ws, size_t ws_size,
                              hipStream_t stream){
  (void)in_sizes; (void)n_in; (void)out_size; (void)ws_size;
  const float* x     = (const float*)d_in[0];
  const float* gamma = (const float*)d_in[1];
  const float* beta  = (const float*)d_in[2];
  const float* wqkv  = (const float*)d_in[3];
  const float* wproj = (const float*)d_in[4];
  const float* bias  = (const float*)d_in[5];
  float* out = (float*)d_out;
  char* ws = (char*)d_ws;
  unsigned short* xn  = (unsigned short*)ws;                       // 32 MB @ 0
  unsigned short* q   = (unsigned short*)(ws + 33554432);          // 4 MB @ 32M
  unsigned short* kb  = (unsigned short*)(ws + 37748736);          // 4 MB @ 36M
  unsigned short* vT2 = (unsigned short*)(ws + 41943040);          // 8 MB @ 40M
  unsigned short* ao  = (unsigned short*)(ws + 50331648);          // 4 MB @ 48M (also absorbs tail over-reads)
  unsigned short* wqkvT  = (unsigned short*)(ws + 54525952);       // 768 KB @ 52M
  unsigned short* wprojT = (unsigned short*)(ws + 54525952 + 786432); // 256 KB
  k_ln  <<<dim3(4608), dim3(256), 0, stream>>>(x, gamma, beta, xn, wqkv, wproj, wqkvT, wprojT, vT2);
  k_qkv <<<dim3(768), dim3(256), 0, stream>>>(xn, wqkvT, q, kb, vT2);
  k_attn<<<dim3(128,8), dim3(256), 0, stream>>>(q, kb, vT2, ao);
  k_proj<<<dim3(128,8), dim3(256), 0, stream>>>(ao, wprojT, bias, out);
}

// Round 23
// 82.874 us; speedup vs baseline: 1.0320x; 1.0015x over previous
//
#include <hip/hip_runtime.h>

// Dims: b=16, n=1024, EMB=1024, INNER=128, HEADS=8, HD=16
#define LOG2E 1.44269504088896340736f
#define QSCALE (0.08838834764831845f * LOG2E)   // INNER^-0.5 * log2(e)

using short8 = __attribute__((ext_vector_type(8))) short;
using f32x4  = __attribute__((ext_vector_type(4))) float;
using f32x16 = __attribute__((ext_vector_type(16))) float;

union U16B { uint4 u; short8 s; };

typedef __attribute__((address_space(3))) unsigned char lds_byte;
typedef const __attribute__((address_space(1))) unsigned char glb_byte;
#define GLOAD16(gp, lp) __builtin_amdgcn_global_load_lds((glb_byte*)(gp), (lds_byte*)(lp), 16, 0, 0)

static __device__ __forceinline__ unsigned short f2bf(float f){
  union { float f; unsigned int i; } c; c.f = f;
  unsigned int i = c.i;
  i += 0x7fffu + ((i >> 16) & 1u);   // RNE
  return (unsigned short)(i >> 16);
}

// ---------------- K1: LayerNorm (0..4095) + weight cvt (4096..4351) + vT2 constant fill (4352..4607) ----------------
__global__ __launch_bounds__(256) void k_ln(const float* __restrict__ x,
                                            const float* __restrict__ gamma,
                                            const float* __restrict__ beta,
                                            unsigned short* __restrict__ xn,
                                            const float* __restrict__ wqkv,
                                            const float* __restrict__ wproj,
                                            unsigned short* __restrict__ wqkvT,
                                            unsigned short* __restrict__ wprojT,
                                            unsigned short* __restrict__ vT2){
  if (blockIdx.x < 4096){
    const int tok = (blockIdx.x*256 + threadIdx.x) >> 6;
    const int l = threadIdx.x & 63;
    const float4* xr = (const float4*)(x + (size_t)tok*1024);
    float4 v[4];
    #pragma unroll
    for (int i=0;i<4;i++) v[i] = xr[l + i*64];
    float s = 0.f, s2 = 0.f;
    #pragma unroll
    for (int i=0;i<4;i++){
      s  += v[i].x+v[i].y+v[i].z+v[i].w;
      s2 += v[i].x*v[i].x+v[i].y*v[i].y+v[i].z*v[i].z+v[i].w*v[i].w;
    }
    #pragma unroll
    for (int o=32;o;o>>=1){ s += __shfl_xor(s,o); s2 += __shfl_xor(s2,o); }
    float mu   = s*(1.0f/1024.0f);
    float rstd = rsqrtf(s2*(1.0f/1024.0f) - mu*mu + 1e-5f);
    ushort4* xo = (ushort4*)(xn + (size_t)tok*1024);
    #pragma unroll
    for (int i=0;i<4;i++){
      float4 g = ((const float4*)gamma)[l + i*64];
      float4 b = ((const float4*)beta)[l + i*64];
      ushort4 o;
      o.x = f2bf((v[i].x-mu)*rstd*g.x + b.x);
      o.y = f2bf((v[i].y-mu)*rstd*g.y + b.y);
      o.z = f2bf((v[i].z-mu)*rstd*g.z + b.z);
      o.w = f2bf((v[i].w-mu)*rstd*g.w + b.w);
      xo[l + i*64] = o;
    }
  } else if (blockIdx.x < 4352){
    int t = (blockIdx.x - 4096)*256 + threadIdx.x;
    if (t < 49152){
      int n = t>>7, k0 = (t&127)*8;
      float sc = (n < 128) ? QSCALE : 1.0f;
      const float* src = wqkv + (size_t)k0*384 + n;
      ushort4 lo, hi;
      lo.x = f2bf(src[0]*sc);    lo.y = f2bf(src[384]*sc);
      lo.z = f2bf(src[768]*sc);  lo.w = f2bf(src[1152]*sc);
      hi.x = f2bf(src[1536]*sc); hi.y = f2bf(src[1920]*sc);
      hi.z = f2bf(src[2304]*sc); hi.w = f2bf(src[2688]*sc);
      *(ushort4*)(wqkvT + (size_t)n*1024 + k0)     = lo;
      *(ushort4*)(wqkvT + (size_t)n*1024 + k0 + 4) = hi;
    } else {
      int t2 = t - 49152;
      int n = t2>>4, k0 = (t2&15)*8;
      const float* src = wproj + (size_t)k0*1024 + n;
      ushort4 lo, hi;
      lo.x = f2bf(src[0]);    lo.y = f2bf(src[1024]);
      lo.z = f2bf(src[2048]); lo.w = f2bf(src[3072]);
      hi.x = f2bf(src[4096]); hi.y = f2bf(src[5120]);
      hi.z = f2bf(src[6144]); hi.w = f2bf(src[7168]);
      *(ushort4*)(wprojT + (size_t)n*128 + k0)     = lo;
      *(ushort4*)(wprojT + (size_t)n*128 + k0 + 4) = hi;
    }
  } else {
    // vT2 constant rows (A-operand rows 16..31 of every 2KB tile):
    // per tile: 4 blocks of 128 ushorts at bases {128,384,640,896}; within a block,
    // row l31=16+w occupies ushorts w*8..w*8+7; ones (bf16 1.0) iff w==0 (l31=16) or w==4 (l31=20).
    #pragma unroll
    for (int i=0;i<4;i++){
      int c = (blockIdx.x - 4352)*1024 + i*256 + threadIdx.x;  // 262144 uint4 chunks
      int tile = c>>6, k = c&63;
      int sub = k>>4, w = k&15;
      unsigned int val = (w==0 || w==4) ? 0x3F803F80u : 0u;
      unsigned short* dp = vT2 + (size_t)tile*1024 + 128 + sub*256 + w*8;
      *(uint4*)dp = make_uint4(val,val,val,val);
    }
  }
}

// ---------------- K2: QKV GEMM (M=16384,K=1024,N=384), BM=64 BN=128 BK=64 ----------------
// grid 768 (1-D, XCD-affinity swizzled), 4 waves; double-buffered, counted vmcnt
__global__ __launch_bounds__(256) void k_qkv(const unsigned short* __restrict__ xn,
                                             const unsigned short* __restrict__ wT,
                                             unsigned short* __restrict__ q,
                                             unsigned short* __restrict__ kbuf,
                                             unsigned short* __restrict__ vT2){
  __shared__ __align__(16) unsigned short sm[2][64*64 + 128*64]; // 2 x 24KB
  const int tid = threadIdx.x;
  const int w = tid>>6, l = tid&63;
  const int bid = blockIdx.x;
  const int X = bid & 7, j = bid >> 3;          // j in 0..95
  const int g = X*32 + (j/3);                   // m-group 0..255
  const int sec = j % 3;
  const int m0 = g*64;
  const int nb = sec*128;
  const int wm = (w>>1)*32, wn = (w&1)*64;
  f32x4 acc[2][4] = {};

  auto stage = [&](int buf, int k0){
    unsigned short* sA = &sm[buf][0];
    unsigned short* sB = &sm[buf][4096];
    #pragma unroll
    for (int i=0;i<2;i++){
      int chunk = i*256 + tid;
      int row = chunk>>3;
      int ch = (tid&7) ^ (row&7);
      GLOAD16(xn + (size_t)(m0+row)*1024 + k0 + ch*8,
              (char*)sA + (i*256 + w*64)*16);
    }
    #pragma unroll
    for (int i=0;i<4;i++){
      int chunk = i*256 + tid;
      int row = chunk>>3;
      int ch = (tid&7) ^ (row&7);
      GLOAD16(wT + (size_t)(nb+row)*1024 + k0 + ch*8,
              (char*)sB + (i*256 + w*64)*16);
    }
  };

  stage(0, 0);
  for (int t=0; t<16; ++t){
    const int cur = t & 1;
    if (t < 15){
      stage(cur^1, (t+1)<<6);
      asm volatile("s_waitcnt vmcnt(6)" ::: "memory");
    } else {
      asm volatile("s_waitcnt vmcnt(0)" ::: "memory");
    }
    __builtin_amdgcn_s_barrier();
    const unsigned short* sA = &sm[cur][0];
    const unsigned short* sB = &sm[cur][4096];
    #pragma unroll
    for (int s=0; s<2; ++s){
      short8 af[2], bfr[4];
      #pragma unroll
      for (int i=0;i<2;i++){
        int row = wm + i*16 + (l&15);
        U16B ta; ta.u = *(const uint4*)((const char*)sA + row*128 + ((s*64 + (l>>4)*16) ^ ((row&7)<<4)));
        af[i] = ta.s;
      }
      #pragma unroll
      for (int jj=0;jj<4;jj++){
        int col = wn + jj*16 + (l&15);
        U16B tb; tb.u = *(const uint4*)((const char*)sB + col*128 + ((s*64 + (l>>4)*16) ^ ((col&7)<<4)));
        bfr[jj] = tb.s;
      }
      #pragma unroll
      for (int i=0;i<2;i++)
        #pragma unroll
        for (int jj=0;jj<4;jj++)
          acc[i][jj] = __builtin_amdgcn_mfma_f32_16x16x32_bf16(af[i], bfr[jj], acc[i][jj], 0,0,0);
    }
    __builtin_amdgcn_s_barrier();
  }

  const int b  = m0 >> 10;
  const int n0 = m0 & 1023;
  unsigned short* ep = &sm[0][0];
  if (sec < 2){
    #pragma unroll
    for (int fm=0; fm<2; ++fm)
      #pragma unroll
      for (int fn=0; fn<4; ++fn){
        int colf = wn + fn*16 + (l&15);
        #pragma unroll
        for (int i=0;i<4;i++){
          int row = wm + fm*16 + (l>>4)*4 + i;
          *(unsigned short*)((char*)ep + row*256 + ((2*colf) ^ ((row&15)<<4))) = f2bf(acc[fm][fn][i]);
        }
      }
    __syncthreads();
    unsigned short* dst = (sec==0) ? q : kbuf;
    #pragma unroll
    for (int it=0; it<4; ++it){
      int chunk = it*256 + tid;
      int tokl = chunk>>4, cc = chunk&15;
      uint4 vv = *(const uint4*)((const char*)ep + tokl*256 + ((cc*16) ^ ((tokl&15)<<4)));
      int h = cc>>1, d0 = (cc&1)*8;
      *(uint4*)(dst + ((size_t)(b*8 + h)*1024 + n0 + tokl)*16 + d0) = vv;
    }
  } else {
    // vT2 fragment-ordered layout: tile = 2KB = 32 A-rows x 32 token-slots;
    // element (d, pos q..q+3 runs) at ushort off = (q&24)*32 + d*8 + (q&4).
    // Token->position permutation identical to R17 (pos1 = (cc&1)*4 + (cc&2)*8).
    #pragma unroll
    for (int fm=0; fm<2; ++fm)
      #pragma unroll
      for (int fn=0; fn<4; ++fn){
        int colf = wn + fn*16 + (l&15);
        int r0 = wm + fm*16 + (l>>4)*4;
        ushort4 pk;
        pk.x = f2bf(acc[fm][fn][0]); pk.y = f2bf(acc[fm][fn][1]);
        pk.z = f2bf(acc[fm][fn][2]); pk.w = f2bf(acc[fm][fn][3]);
        *(ushort4*)((char*)ep + colf*128 + ((2*r0) ^ ((colf&7)<<4))) = pk;
      }
    __syncthreads();
    #pragma unroll
    for (int it=0; it<4; ++it){
      int chunk = it*256 + tid;
      int f = chunk>>3, cc = chunk&7;
      uint4 vv = *(const uint4*)((const char*)ep + f*128 + ((cc*16) ^ ((f&7)<<4)));
      int h = f>>4, d = f&15;
      int tile = (n0>>5) + (cc>>2);
      int q1 = (cc&1)*4 + (cc&2)*8;
      int q2 = q1 + 8;
      unsigned short* tb = vT2 + ((size_t)(b*8 + h)*32 + tile)*1024 + d*8;
      *(uint2*)(tb + (q1&24)*32 + (q1&4)) = make_uint2(vv.x, vv.y);
      *(uint2*)(tb + (q2&24)*32 + (q2&4)) = make_uint2(vv.z, vv.w);
    }
  }
}

// ---------------- K3: flash attention, delayed-PV + fragment-ordered V (single-segment loads) ----------------
// grid (128 bh, 8 qc), 4 waves x 32 q-rows
__global__ __launch_bounds__(256) void k_attn(const unsigned short* __restrict__ q,
                                              const unsigned short* __restrict__ kbuf,
                                              const unsigned short* __restrict__ vT2,
                                              unsigned short* __restrict__ aout){
  const int bh = blockIdx.x;
  const int qc = blockIdx.y;
  const int w = threadIdx.x>>6, l = threadIdx.x&63;
  const int l31 = l&31, hi = l>>5;
  const int h = bh & 7;
  const int qrow = qc*128 + w*32 + l31;
  U16B qf_u; qf_u.u = *(const uint4*)(q + ((size_t)bh*1024 + qrow)*16 + hi*8);
  const short8 qf = qf_u.s;
  const unsigned short* kptr = kbuf + (size_t)bh*16384 + (size_t)l31*16 + hi*8;
  // fragment-ordered V: lane l's 16B at l*8 ushorts within each 1KB half-tile
  const unsigned short* vptr = vT2 + (size_t)bh*32768 + (size_t)l*8;
  f32x16 acc = {};
  const f32x16 zz = {};

  U16B kf; kf.u = *(const uint4*)kptr; kptr += 512;
  U16B kn; kn.u = *(const uint4*)kptr; kptr += 512;
  f32x16 sv = __builtin_amdgcn_mfma_f32_32x32x16_bf16(kf.s, qf, zz, 0,0,0);
  unsigned int u8_0=0,u8_1=0,u8_2=0,u8_3=0,u8_4=0,u8_5=0,u8_6=0,u8_7=0;
  U16B vp0, vp1;
  vp0.u = make_uint4(0,0,0,0); vp1.u = make_uint4(0,0,0,0);   // P(-1)=0, values unused

  for (int t=0; t<32; ++t){
    U16B knn; knn.u = *(const uint4*)kptr; kptr += 512;
    U16B vn0, vn1;
    vn0.u = *(const uint4*)vptr;
    vn1.u = *(const uint4*)(vptr + 512);
    vptr += 1024;
    f32x16 svn = __builtin_amdgcn_mfma_f32_32x32x16_bf16(kn.s, qf, zz, 0,0,0);
    unsigned int un0,un1,un2,un3,un4,un5,un6,un7;
    {
      float a,b;
      a=__builtin_amdgcn_exp2f(sv[0]);  b=__builtin_amdgcn_exp2f(sv[1]);
      asm("v_cvt_pk_bf16_f32 %0, %1, %2" : "=v"(un0) : "v"(a), "v"(b));
      a=__builtin_amdgcn_exp2f(sv[2]);  b=__builtin_amdgcn_exp2f(sv[3]);
      asm("v_cvt_pk_bf16_f32 %0, %1, %2" : "=v"(un1) : "v"(a), "v"(b));
      a=__builtin_amdgcn_exp2f(sv[4]);  b=__builtin_amdgcn_exp2f(sv[5]);
      asm("v_cvt_pk_bf16_f32 %0, %1, %2" : "=v"(un2) : "v"(a), "v"(b));
      a=__builtin_amdgcn_exp2f(sv[6]);  b=__builtin_amdgcn_exp2f(sv[7]);
      asm("v_cvt_pk_bf16_f32 %0, %1, %2" : "=v"(un3) : "v"(a), "v"(b));
      a=__builtin_amdgcn_exp2f(sv[8]);  b=__builtin_amdgcn_exp2f(sv[9]);
      asm("v_cvt_pk_bf16_f32 %0, %1, %2" : "=v"(un4) : "v"(a), "v"(b));
      a=__builtin_amdgcn_exp2f(sv[10]); b=__builtin_amdgcn_exp2f(sv[11]);
      asm("v_cvt_pk_bf16_f32 %0, %1, %2" : "=v"(un5) : "v"(a), "v"(b));
      a=__builtin_amdgcn_exp2f(sv[12]); b=__builtin_amdgcn_exp2f(sv[13]);
      asm("v_cvt_pk_bf16_f32 %0, %1, %2" : "=v"(un6) : "v"(a), "v"(b));
      a=__builtin_amdgcn_exp2f(sv[14]); b=__builtin_amdgcn_exp2f(sv[15]);
      asm("v_cvt_pk_bf16_f32 %0, %1, %2" : "=v"(un7) : "v"(a), "v"(b));
    }
    U16B p0, p1;
    p0.u.x = u8_0; p0.u.y = u8_1; p0.u.z = u8_2; p0.u.w = u8_3;
    p1.u.x = u8_4; p1.u.y = u8_5; p1.u.z = u8_6; p1.u.w = u8_7;
    __builtin_amdgcn_s_setprio(1);
    acc = __builtin_amdgcn_mfma_f32_32x32x16_bf16(vp0.s, p0.s, acc, 0,0,0);
    acc = __builtin_amdgcn_mfma_f32_32x32x16_bf16(vp1.s, p1.s, acc, 0,0,0);
    __builtin_amdgcn_s_setprio(0);
    sv = svn; kn = knn;
    u8_0=un0; u8_1=un1; u8_2=un2; u8_3=un3; u8_4=un4; u8_5=un5; u8_6=un6; u8_7=un7;
    vp0 = vn0; vp1 = vn1;
  }
  {
    U16B p0, p1;
    p0.u.x = u8_0; p0.u.y = u8_1; p0.u.z = u8_2; p0.u.w = u8_3;
    p1.u.x = u8_4; p1.u.y = u8_5; p1.u.z = u8_6; p1.u.w = u8_7;
    acc = __builtin_amdgcn_mfma_f32_32x32x16_bf16(vp0.s, p0.s, acc, 0,0,0);
    acc = __builtin_amdgcn_mfma_f32_32x32x16_bf16(vp1.s, p1.s, acc, 0,0,0);
  }
  float inv = 1.0f/acc[8];
  const size_t tok = (size_t)(bh>>3)*1024 + qrow;
  ushort4 o;
  o.x = f2bf(acc[0]*inv); o.y = f2bf(acc[1]*inv); o.z = f2bf(acc[2]*inv); o.w = f2bf(acc[3]*inv);
  *(ushort4*)(aout + tok*128 + h*16 + hi*4) = o;
  o.x = f2bf(acc[4]*inv); o.y = f2bf(acc[5]*inv); o.z = f2bf(acc[6]*inv); o.w = f2bf(acc[7]*inv);
  *(ushort4*)(aout + tok*128 + h*16 + 8 + hi*4) = o;
}

// ---------------- K4: out-projection (M=16384,K=128,N=1024) + bias ----------------
__global__ __launch_bounds__(256) void k_proj(const unsigned short* __restrict__ aout,
                                              const unsigned short* __restrict__ wT, // [1024 n][128 k]
                                              const float* __restrict__ bias,
                                              float* __restrict__ out){
  __shared__ __align__(16) unsigned short sA[128*128]; // [tok][k], 256B rows, XOR (row&15)<<4
  __shared__ __align__(16) unsigned short sB[128*128]; // [n][k], same
  const int tid = threadIdx.x;
  const int w = tid>>6, l = tid&63;
  const int m0 = blockIdx.x*128, nb = blockIdx.y*128;
  #pragma unroll
  for (int i=0;i<8;i++){
    int chunk = i*256 + tid;
    int row = chunk>>4;
    int ch = (tid&15) ^ (row&15);
    GLOAD16(aout + (size_t)(m0+row)*128 + ch*8, (char*)sA + (i*256 + w*64)*16);
  }
  #pragma unroll
  for (int i=0;i<8;i++){
    int chunk = i*256 + tid;
    int row = chunk>>4;
    int ch = (tid&15) ^ (row&15);
    GLOAD16(wT + (size_t)(nb+row)*128 + ch*8, (char*)sB + (i*256 + w*64)*16);
  }
  __syncthreads();
  const int wm = (w>>1)*64, wn = (w&1)*64;
  f32x4 acc[4][4] = {};
  #pragma unroll
  for (int s=0; s<4; ++s){
    short8 af[4], bfr[4];
    #pragma unroll
    for (int i=0;i<4;i++){
      int row = wm + i*16 + (l&15);
      U16B ta; ta.u = *(const uint4*)((const char*)sA + row*256 + ((s*64 + (l>>4)*16) ^ ((row&15)<<4)));
      af[i] = ta.s;
      int col = wn + i*16 + (l&15);
      U16B tb; tb.u = *(const uint4*)((const char*)sB + col*256 + ((s*64 + (l>>4)*16) ^ ((col&15)<<4)));
      bfr[i] = tb.s;
    }
    #pragma unroll
    for (int i=0;i<4;i++)
      #pragma unroll
      for (int j=0;j<4;j++)
        acc[i][j] = __builtin_amdgcn_mfma_f32_16x16x32_bf16(af[i], bfr[j], acc[i][j], 0,0,0);
  }
  #pragma unroll
  for (int fn=0; fn<4; ++fn){
    int col = nb + wn + fn*16 + (l&15);
    float bv = bias[col];
    #pragma unroll
    for (int fm=0; fm<4; ++fm)
      #pragma unroll
      for (int i=0;i<4;i++)
        out[(size_t)(m0 + wm + fm*16 + (l>>4)*4 + i)*1024 + col] = acc[fm][fn][i] + bv;
  }
}

extern "C" void kernel_launch(void* const* d_in, const int* in_sizes, int n_in,
                              void* d_out, int out_size, void* d_ws, size_t ws_size,
                              hipStream_t stream){
  (void)in_sizes; (void)n_in; (void)out_size; (void)ws_size;
  const float* x     = (const float*)d_in[0];
  const float* gamma = (const float*)d_in[1];
  const float* beta  = (const float*)d_in[2];
  const float* wqkv  = (const float*)d_in[3];
  const float* wproj = (const float*)d_in[4];
  const float* bias  = (const float*)d_in[5];
  float* out = (float*)d_out;
  char* ws = (char*)d_ws;
  unsigned short* xn  = (unsigned short*)ws;                       // 32 MB @ 0
  unsigned short* q   = (unsigned short*)(ws + 33554432);          // 4 MB @ 32M
  unsigned short* kb  = (unsigned short*)(ws + 37748736);          // 4 MB @ 36M
  unsigned short* vT2 = (unsigned short*)(ws + 41943040);          // 8 MB @ 40M
  unsigned short* ao  = (unsigned short*)(ws + 50331648);          // 4 MB @ 48M (also absorbs tail over-reads)
  unsigned short* wqkvT  = (unsigned short*)(ws + 54525952);       // 768 KB @ 52M
  unsigned short* wprojT = (unsigned short*)(ws + 54525952 + 786432); // 256 KB
  k_ln  <<<dim3(4608), dim3(256), 0, stream>>>(x, gamma, beta, xn, wqkv, wproj, wqkvT, wprojT, vT2);
  k_qkv <<<dim3(768), dim3(256), 0, stream>>>(xn, wqkvT, q, kb, vT2);
  k_attn<<<dim3(128,8), dim3(256), 0, stream>>>(q, kb, vT2, ao);
  k_proj<<<dim3(128,8), dim3(256), 0, stream>>>(ao, wprojT, bias, out);
}